// Round 1
// baseline (422.325 us; speedup 1.0000x reference)
//
#include <hip/hip_runtime.h>

// Problem constants (fixed by setup_inputs)
#define N_IMG 4
#define E_DIM 16
#define H_DIM 768
#define W_DIM 768
#define P_PIX (H_DIM * W_DIM)   // 589824 pixels per image
#define C_CL 32
#define PAD 17                  // LDS leading-dim pad: 17 coprime w/ 32 banks

#define DELTA_VAR 0.5f
#define DELTA_DIST 2.0f
#define GAMMA_W 0.001f
#define EPS_F 1e-12f

// Workspace layout (floats):
//   [0,    2048): sums   [N][C][E]
//   [2048, 2176): counts [N][C]
//   [2176, 2304): hinge  [N][C]
#define WS_SUMS 0
#define WS_CNT 2048
#define WS_HINGE 2176
#define WS_TOTAL 2304

// Pixels per block: 256 threads x 8 px = 2048 -> 288 blocks per image.
#define PX_PER_BLOCK 2048
#define BLOCKS_X (P_PIX / PX_PER_BLOCK)  // 288

__device__ __forceinline__ void gatomic_add(float* p, float v) {
#if defined(__HIP_DEVICE_COMPILE__)
  unsafeAtomicAdd(p, v);  // hw global_atomic_add_f32 on gfx950
#else
  atomicAdd(p, v);
#endif
}

__global__ __launch_bounds__(256) void zero_ws(float* __restrict__ ws) {
  for (int i = threadIdx.x; i < WS_TOTAL; i += 256) ws[i] = 0.f;
}

// Pass 1: per-cluster sums and counts.
__global__ __launch_bounds__(256) void pass1(const float* __restrict__ input,
                                             const int* __restrict__ target,
                                             float* __restrict__ ws) {
  __shared__ float s_sum[C_CL * PAD];
  __shared__ float s_cnt[C_CL];
  const int tid = threadIdx.x;
  for (int i = tid; i < C_CL * PAD; i += 256) s_sum[i] = 0.f;
  if (tid < C_CL) s_cnt[tid] = 0.f;
  __syncthreads();

  const int n = blockIdx.y;
  const int base = blockIdx.x * PX_PER_BLOCK;
  const float* inp_n = input + (size_t)n * E_DIM * P_PIX;
  const int* tgt_n = target + (size_t)n * P_PIX;

#pragma unroll
  for (int s = 0; s < 2; ++s) {
    const int p = base + s * 1024 + tid * 4;
    const int4 lab = *reinterpret_cast<const int4*>(tgt_n + p);
    atomicAdd(&s_cnt[lab.x], 1.f);
    atomicAdd(&s_cnt[lab.y], 1.f);
    atomicAdd(&s_cnt[lab.z], 1.f);
    atomicAdd(&s_cnt[lab.w], 1.f);
#pragma unroll
    for (int e = 0; e < E_DIM; ++e) {
      const float4 v =
          *reinterpret_cast<const float4*>(inp_n + (size_t)e * P_PIX + p);
      atomicAdd(&s_sum[lab.x * PAD + e], v.x);
      atomicAdd(&s_sum[lab.y * PAD + e], v.y);
      atomicAdd(&s_sum[lab.z * PAD + e], v.z);
      atomicAdd(&s_sum[lab.w * PAD + e], v.w);
    }
  }
  __syncthreads();

  float* gsum = ws + WS_SUMS + n * C_CL * E_DIM;
  for (int i = tid; i < C_CL * E_DIM; i += 256) {
    const int c = i >> 4, e = i & 15;
    gatomic_add(&gsum[i], s_sum[c * PAD + e]);
  }
  if (tid < C_CL) gatomic_add(ws + WS_CNT + n * C_CL + tid, s_cnt[tid]);
}

// Pass 2: per-pixel hinge to own-cluster mean; accumulate per-cluster hinge sums.
__global__ __launch_bounds__(256) void pass2(const float* __restrict__ input,
                                             const int* __restrict__ target,
                                             float* __restrict__ ws) {
  __shared__ float s_mean[C_CL * PAD];
  __shared__ float s_hinge[C_CL];
  const int tid = threadIdx.x;
  const int n = blockIdx.y;
  const float* gsum = ws + WS_SUMS + n * C_CL * E_DIM;
  const float* gcnt = ws + WS_CNT + n * C_CL;
  for (int i = tid; i < C_CL * E_DIM; i += 256) {
    const int c = i >> 4, e = i & 15;
    s_mean[c * PAD + e] = gsum[i] / gcnt[c];
  }
  if (tid < C_CL) s_hinge[tid] = 0.f;
  __syncthreads();

  const int base = blockIdx.x * PX_PER_BLOCK;
  const float* inp_n = input + (size_t)n * E_DIM * P_PIX;
  const int* tgt_n = target + (size_t)n * P_PIX;

#pragma unroll
  for (int s = 0; s < 2; ++s) {
    const int p = base + s * 1024 + tid * 4;
    const int4 lab = *reinterpret_cast<const int4*>(tgt_n + p);
    float ax = 0.f, ay = 0.f, az = 0.f, aw = 0.f;
#pragma unroll
    for (int e = 0; e < E_DIM; ++e) {
      const float4 v =
          *reinterpret_cast<const float4*>(inp_n + (size_t)e * P_PIX + p);
      const float dx = v.x - s_mean[lab.x * PAD + e];
      const float dy = v.y - s_mean[lab.y * PAD + e];
      const float dz = v.z - s_mean[lab.z * PAD + e];
      const float dw = v.w - s_mean[lab.w * PAD + e];
      ax += dx * dx; ay += dy * dy; az += dz * dz; aw += dw * dw;
    }
    float d, h;
    d = sqrtf(fmaxf(ax, EPS_F)); h = fmaxf(d - DELTA_VAR, 0.f);
    atomicAdd(&s_hinge[lab.x], h * h);
    d = sqrtf(fmaxf(ay, EPS_F)); h = fmaxf(d - DELTA_VAR, 0.f);
    atomicAdd(&s_hinge[lab.y], h * h);
    d = sqrtf(fmaxf(az, EPS_F)); h = fmaxf(d - DELTA_VAR, 0.f);
    atomicAdd(&s_hinge[lab.z], h * h);
    d = sqrtf(fmaxf(aw, EPS_F)); h = fmaxf(d - DELTA_VAR, 0.f);
    atomicAdd(&s_hinge[lab.w], h * h);
  }
  __syncthreads();
  if (tid < C_CL) gatomic_add(ws + WS_HINGE + n * C_CL + tid, s_hinge[tid]);
}

// Finalize: variance term + pairwise distance term + regularizer -> scalar.
__global__ __launch_bounds__(256) void finalize(const float* __restrict__ ws,
                                                float* __restrict__ out) {
  __shared__ float s_mean[N_IMG * C_CL * E_DIM];  // 2048 floats
  __shared__ float red[256];
  const int tid = threadIdx.x;
  for (int i = tid; i < N_IMG * C_CL * E_DIM; i += 256) {
    s_mean[i] = ws[WS_SUMS + i] / ws[WS_CNT + (i >> 4)];
  }
  __syncthreads();

  float acc = 0.f;
  // variance + regularizer over 128 (n,c) cells
  for (int i = tid; i < N_IMG * C_CL; i += 256) {
    const float cnt = ws[WS_CNT + i];
    const float h = ws[WS_HINGE + i];
    acc += (h / cnt) * (1.0f / C_CL);
    float nrm2 = 0.f;
    const float* m = s_mean + i * E_DIM;
#pragma unroll
    for (int e = 0; e < E_DIM; ++e) nrm2 += m[e] * m[e];
    acc += GAMMA_W * sqrtf(fmaxf(nrm2, EPS_F)) * (1.0f / C_CL);
  }
  // pairwise distance term: 4 * 32 * 32 cells
  for (int t = tid; t < N_IMG * C_CL * C_CL; t += 256) {
    const int n = t / (C_CL * C_CL);
    const int r = t - n * C_CL * C_CL;
    const int a = r >> 5, b = r & 31;
    if (a != b) {
      const float* ma = s_mean + (n * C_CL + a) * E_DIM;
      const float* mb = s_mean + (n * C_CL + b) * E_DIM;
      float d2 = 0.f;
#pragma unroll
      for (int e = 0; e < E_DIM; ++e) {
        const float df = ma[e] - mb[e];
        d2 += df * df;
      }
      const float dist = sqrtf(fmaxf(d2, EPS_F));
      const float hd = fmaxf(2.f * DELTA_DIST - dist, 0.f);
      acc += hd * hd * (1.0f / (C_CL * (C_CL - 1)));
    }
  }

  red[tid] = acc;
  __syncthreads();
  for (int s = 128; s > 0; s >>= 1) {
    if (tid < s) red[tid] += red[tid + s];
    __syncthreads();
  }
  if (tid == 0) out[0] = red[0] * (1.0f / N_IMG);
}

extern "C" void kernel_launch(void* const* d_in, const int* in_sizes, int n_in,
                              void* d_out, int out_size, void* d_ws,
                              size_t ws_size, hipStream_t stream) {
  const float* input = (const float*)d_in[0];
  const int* target = (const int*)d_in[1];
  float* ws = (float*)d_ws;
  float* out = (float*)d_out;

  zero_ws<<<1, 256, 0, stream>>>(ws);
  dim3 grid(BLOCKS_X, N_IMG);
  pass1<<<grid, 256, 0, stream>>>(input, target, ws);
  pass2<<<grid, 256, 0, stream>>>(input, target, ws);
  finalize<<<1, 256, 0, stream>>>(ws, out);
}

// Round 2
// 272.253 us; speedup vs baseline: 1.5512x; 1.5512x over previous
//
#include <hip/hip_runtime.h>

// Problem constants (fixed by setup_inputs)
#define N_IMG 4
#define E_DIM 16
#define H_DIM 768
#define W_DIM 768
#define P_PIX (H_DIM * W_DIM)   // 589824 pixels per image
#define C_CL 32
#define PAD 17                  // mean table pad (bank = (17*lab+e)%32, bijective in lab)
#define PRIV 33                 // private-histogram stride: bank = (tid+lab)%32

#define DELTA_VAR 0.5f
#define DELTA_DIST 2.0f
#define GAMMA_W 0.001f
#define EPS_F 1e-12f

// Workspace layout (floats):
//   [0,    2048): sums   [N][C][E]
//   [2048, 2176): counts [N][C]
//   [2176, 2304): hinge  [N][C]
#define WS_SUMS 0
#define WS_CNT 2048
#define WS_HINGE 2176
#define WS_TOTAL 2304

#define STEPS 32
#define PX_PER_BLOCK 2048                // 64 px/step * 32 steps
#define BLOCKS_X (P_PIX / PX_PER_BLOCK)  // 288

__device__ __forceinline__ void gatomic_add(float* p, float v) {
#if defined(__HIP_DEVICE_COMPILE__)
  unsafeAtomicAdd(p, v);  // hw global_atomic_add_f32 on gfx950
#else
  atomicAdd(p, v);
#endif
}

// Pass 1: per-cluster sums and counts via per-thread private LDS histograms.
// Thread layout: wave w = tid>>6, lane l = tid&63; e = 4*w + (l>>4); px16 = l&15.
// Each thread accumulates its single e-dim over 4 consecutive pixels/step into
// a private 32-slot region (stride 33 -> conflict-free-ish, zero atomics).
__global__ __launch_bounds__(256) void pass1(const float* __restrict__ input,
                                             const int* __restrict__ target,
                                             float* __restrict__ ws) {
  __shared__ float s_priv[256 * PRIV];  // 33792 B
  __shared__ float s_cntp[16 * PRIV];   // 2112 B (e==0 threads count pixels)
  const int tid = threadIdx.x;
  const int w = tid >> 6, l = tid & 63;
  const int e = (w << 2) + (l >> 4);
  const int px16 = l & 15;

  float* priv = s_priv + tid * PRIV;
#pragma unroll
  for (int i = 0; i < 32; ++i) priv[i] = 0.f;
  if (tid < 16) {
#pragma unroll
    for (int i = 0; i < 32; ++i) s_cntp[tid * PRIV + i] = 0.f;
  }
  __syncthreads();

  const int n = blockIdx.y;
  const float* inp_e = input + ((size_t)n * E_DIM + e) * P_PIX;
  const int* tgt_n = target + (size_t)n * P_PIX;
  const int base = blockIdx.x * PX_PER_BLOCK + px16 * 4;
  float* cpriv = s_cntp + px16 * PRIV;

  // software pipeline: keep the global stream ahead of the LDS RMW chain
  int4 lab = *reinterpret_cast<const int4*>(tgt_n + base);
  float4 v = *reinterpret_cast<const float4*>(inp_e + base);
  for (int s = 0; s < STEPS; ++s) {
    const int4 labc = lab;
    const float4 vc = v;
    if (s + 1 < STEPS) {
      const int p = base + (s + 1) * 64;
      lab = *reinterpret_cast<const int4*>(tgt_n + p);
      v = *reinterpret_cast<const float4*>(inp_e + p);
    }
    priv[labc.x] += vc.x;
    priv[labc.y] += vc.y;
    priv[labc.z] += vc.z;
    priv[labc.w] += vc.w;
    if (tid < 16) {  // e == 0 group covers every pixel exactly once
      cpriv[labc.x] += 1.f;
      cpriv[labc.y] += 1.f;
      cpriv[labc.z] += 1.f;
      cpriv[labc.w] += 1.f;
    }
  }
  __syncthreads();

  // Block flush: sum the 16 private regions sharing each e, one global atomic.
  float* gsum = ws + WS_SUMS + n * C_CL * E_DIM;
#pragma unroll
  for (int i = tid; i < C_CL * E_DIM; i += 256) {
    const int c = i >> 4, ee = i & 15;
    const int t0 = (ee >> 2) * 64 + (ee & 3) * 16;
    float val = 0.f;
#pragma unroll
    for (int k = 0; k < 16; ++k) val += s_priv[(t0 + k) * PRIV + c];
    gatomic_add(&gsum[i], val);
  }
  if (tid < C_CL) {
    float cnt = 0.f;
#pragma unroll
    for (int k = 0; k < 16; ++k) cnt += s_cntp[k * PRIV + tid];
    gatomic_add(ws + WS_CNT + n * C_CL + tid, cnt);
  }
}

// Pass 2: per-pixel hinge to own-cluster mean; private LDS hinge histograms.
__global__ __launch_bounds__(256) void pass2(const float* __restrict__ input,
                                             const int* __restrict__ target,
                                             float* __restrict__ ws) {
  __shared__ float s_mean[C_CL * PAD];
  __shared__ float s_hpriv[256 * PRIV];  // 33792 B
  __shared__ float s_hinge[C_CL];
  const int tid = threadIdx.x;
  const int n = blockIdx.y;
  const float* gsum = ws + WS_SUMS + n * C_CL * E_DIM;
  const float* gcnt = ws + WS_CNT + n * C_CL;
  for (int i = tid; i < C_CL * E_DIM; i += 256) {
    const int c = i >> 4, e = i & 15;
    s_mean[c * PAD + e] = gsum[i] / gcnt[c];
  }
  float* hpriv = s_hpriv + tid * PRIV;
#pragma unroll
  for (int i = 0; i < 32; ++i) hpriv[i] = 0.f;
  if (tid < C_CL) s_hinge[tid] = 0.f;
  __syncthreads();

  const int base = blockIdx.x * PX_PER_BLOCK;
  const float* inp_n = input + (size_t)n * E_DIM * P_PIX;
  const int* tgt_n = target + (size_t)n * P_PIX;

#pragma unroll
  for (int s = 0; s < 2; ++s) {
    const int p = base + s * 1024 + tid * 4;
    const int4 lab = *reinterpret_cast<const int4*>(tgt_n + p);
    float ax = 0.f, ay = 0.f, az = 0.f, aw = 0.f;
#pragma unroll
    for (int e = 0; e < E_DIM; ++e) {
      const float4 v =
          *reinterpret_cast<const float4*>(inp_n + (size_t)e * P_PIX + p);
      const float dx = v.x - s_mean[lab.x * PAD + e];
      const float dy = v.y - s_mean[lab.y * PAD + e];
      const float dz = v.z - s_mean[lab.z * PAD + e];
      const float dw = v.w - s_mean[lab.w * PAD + e];
      ax += dx * dx; ay += dy * dy; az += dz * dz; aw += dw * dw;
    }
    float d, h;
    d = sqrtf(fmaxf(ax, EPS_F)); h = fmaxf(d - DELTA_VAR, 0.f);
    hpriv[lab.x] += h * h;
    d = sqrtf(fmaxf(ay, EPS_F)); h = fmaxf(d - DELTA_VAR, 0.f);
    hpriv[lab.y] += h * h;
    d = sqrtf(fmaxf(az, EPS_F)); h = fmaxf(d - DELTA_VAR, 0.f);
    hpriv[lab.z] += h * h;
    d = sqrtf(fmaxf(aw, EPS_F)); h = fmaxf(d - DELTA_VAR, 0.f);
    hpriv[lab.w] += h * h;
  }
  __syncthreads();

  // Block reduce: 8 row-groups of 32 rows each, then 8-way LDS atomic (tiny).
  {
    const int c = tid & 31, g = tid >> 5;
    float part = 0.f;
#pragma unroll
    for (int r = g * 32; r < g * 32 + 32; ++r) part += s_hpriv[r * PRIV + c];
    atomicAdd(&s_hinge[c], part);
  }
  __syncthreads();
  if (tid < C_CL) gatomic_add(ws + WS_HINGE + n * C_CL + tid, s_hinge[tid]);
}

// Finalize: variance term + pairwise distance term + regularizer -> scalar.
__global__ __launch_bounds__(256) void finalize(const float* __restrict__ ws,
                                                float* __restrict__ out) {
  __shared__ float s_mean[N_IMG * C_CL * E_DIM];  // 2048 floats
  __shared__ float red[256];
  const int tid = threadIdx.x;
  for (int i = tid; i < N_IMG * C_CL * E_DIM; i += 256) {
    s_mean[i] = ws[WS_SUMS + i] / ws[WS_CNT + (i >> 4)];
  }
  __syncthreads();

  float acc = 0.f;
  for (int i = tid; i < N_IMG * C_CL; i += 256) {
    const float cnt = ws[WS_CNT + i];
    const float h = ws[WS_HINGE + i];
    acc += (h / cnt) * (1.0f / C_CL);
    float nrm2 = 0.f;
    const float* m = s_mean + i * E_DIM;
#pragma unroll
    for (int e = 0; e < E_DIM; ++e) nrm2 += m[e] * m[e];
    acc += GAMMA_W * sqrtf(fmaxf(nrm2, EPS_F)) * (1.0f / C_CL);
  }
  for (int t = tid; t < N_IMG * C_CL * C_CL; t += 256) {
    const int n = t / (C_CL * C_CL);
    const int r = t - n * C_CL * C_CL;
    const int a = r >> 5, b = r & 31;
    if (a != b) {
      const float* ma = s_mean + (n * C_CL + a) * E_DIM;
      const float* mb = s_mean + (n * C_CL + b) * E_DIM;
      float d2 = 0.f;
#pragma unroll
      for (int e = 0; e < E_DIM; ++e) {
        const float df = ma[e] - mb[e];
        d2 += df * df;
      }
      const float dist = sqrtf(fmaxf(d2, EPS_F));
      const float hd = fmaxf(2.f * DELTA_DIST - dist, 0.f);
      acc += hd * hd * (1.0f / (C_CL * (C_CL - 1)));
    }
  }

  red[tid] = acc;
  __syncthreads();
  for (int s = 128; s > 0; s >>= 1) {
    if (tid < s) red[tid] += red[tid + s];
    __syncthreads();
  }
  if (tid == 0) out[0] = red[0] * (1.0f / N_IMG);
}

extern "C" void kernel_launch(void* const* d_in, const int* in_sizes, int n_in,
                              void* d_out, int out_size, void* d_ws,
                              size_t ws_size, hipStream_t stream) {
  const float* input = (const float*)d_in[0];
  const int* target = (const int*)d_in[1];
  float* ws = (float*)d_ws;
  float* out = (float*)d_out;

  hipMemsetAsync(ws, 0, WS_TOTAL * sizeof(float), stream);
  dim3 grid(BLOCKS_X, N_IMG);
  pass1<<<grid, 256, 0, stream>>>(input, target, ws);
  pass2<<<grid, 256, 0, stream>>>(input, target, ws);
  finalize<<<1, 256, 0, stream>>>(ws, out);
}